// Round 17
// baseline (46.499 us; speedup 1.0000x reference)
//
#include <hip/hip_runtime.h>
#include <hip/hip_cooperative_groups.h>

// WiredRNN one step. SINGLE cooperative kernel: {slab partition || transpose}
// -> grid.sync() -> {per-range sort + register gather + tanh + output}.
// NO f32 atomics (measured wall: 25.6M LDS f32 atomicAdd = 170-180us).
// Phase-2 stages records in REGISTERS (one staging read, not two).
// Fallbacks: r16 two-kernel path if coop capacity check fails; atomic path
// if workspace too small.
// inputs: 0:x(B,512) 1:states(B,N) 2:weight(E) 3:bias(N) 4:response(N)
//         5:edge_src(E int32) 6:edge_dst(E int32)
// out: y(B,256) then new_states(B,N), f32, concatenated flat.

#define BATCH 32
#define N_IN 512
#define N_OUT 256
#define RB_LOG 6
#define RB 64            // nodes per range
#define CAPL 2048        // records per accfin round (16KB LDS)
#define MAXR 2048        // max ranges (fallback fpart LDS)
#define PCHC 4096        // edges per partition block, coop (8/thr @512)
#define PCHF 8192        // edges per partition block, fallback (8/thr @1024)
#define SMEM_INTS 6336   // 25344 B: acc(2112f) + sorted(2048 int2) + 2*RB

static __device__ __forceinline__ unsigned short f2bf(float f) {
    unsigned u = __float_as_uint(f);
    unsigned r = (u + 0x7fffu + ((u >> 16) & 1u)) >> 16;   // RNE
    return (unsigned short)r;
}

// ================= cooperative fused kernel =================
__global__ __launch_bounds__(512, 8)
void fused_kernel(const float* __restrict__ s,
                  unsigned short* __restrict__ sTb,
                  const int* __restrict__ edge_src,
                  const int* __restrict__ edge_dst,
                  const float* __restrict__ weight,
                  int* __restrict__ cursors,
                  int2* __restrict__ staging,
                  const float* __restrict__ x,
                  const float* __restrict__ bias,
                  const float* __restrict__ response,
                  float* __restrict__ ns, float* __restrict__ y,
                  int N, int E, int R, int CAP, int PB, int TG) {
    __shared__ int smem[SMEM_INTS];
    int tid = threadIdx.x;
    int bid = blockIdx.x;

    // ---------------- phase 1 ----------------
    if (bid < PB) {
        // partition: 4096 edges, 8/thread in registers
        int* h    = smem;
        int* lcur = smem + R;
        for (int i = tid; i < R; i += 512) h[i] = 0;
        __syncthreads();
        int e0 = bid * PCHC;
        int e1 = min(e0 + PCHC, E);
        int dd[8], ss[8]; float ww[8];
#pragma unroll
        for (int it = 0; it < 2; ++it) {
            int e = e0 + it * 2048 + tid * 4;
#pragma unroll
            for (int j = 0; j < 4; ++j) dd[it * 4 + j] = -1;
            if (e + 4 <= e1) {
                int4 d4 = *reinterpret_cast<const int4*>(edge_dst + e);
                int4 s4 = *reinterpret_cast<const int4*>(edge_src + e);
                float4 w4 = *reinterpret_cast<const float4*>(weight + e);
                dd[it*4+0]=d4.x; dd[it*4+1]=d4.y; dd[it*4+2]=d4.z; dd[it*4+3]=d4.w;
                ss[it*4+0]=s4.x; ss[it*4+1]=s4.y; ss[it*4+2]=s4.z; ss[it*4+3]=s4.w;
                ww[it*4+0]=w4.x; ww[it*4+1]=w4.y; ww[it*4+2]=w4.z; ww[it*4+3]=w4.w;
            } else {
#pragma unroll
                for (int j = 0; j < 4; ++j) {
                    if (e + j < e1) {
                        dd[it*4+j] = edge_dst[e + j];
                        ss[it*4+j] = edge_src[e + j];
                        ww[it*4+j] = weight[e + j];
                    }
                }
            }
#pragma unroll
            for (int j = 0; j < 4; ++j) {
                int idx = it * 4 + j;
                if (dd[idx] >= N_IN) atomicAdd(&h[dd[idx] >> RB_LOG], 1);
            }
        }
        __syncthreads();
        for (int i = tid; i < R; i += 512) {
            int c = h[i];
            lcur[i] = c ? (i * CAP + atomicAdd(&cursors[i], c)) : 0;
        }
        __syncthreads();
#pragma unroll
        for (int idx = 0; idx < 8; ++idx) {
            if (dd[idx] >= N_IN) {
                int rng = dd[idx] >> RB_LOG;
                int pos = atomicAdd(&lcur[rng], 1);
                if (pos < (rng + 1) * CAP)
                    staging[pos] = make_int2(((dd[idx] & (RB - 1)) << 16) | ss[idx],
                                             __float_as_int(ww[idx]));
            }
        }
    } else if (bid < PB + TG) {
        // transpose 4 tiles of 32 nodes, 512 threads
        float* tiles = (float*)smem;             // [4][1056] = 16.9 KB
        int tx = tid & 31;
        int ty0 = tid >> 5;                      // 0..15
        int nb = (bid - PB) * 128;
#pragma unroll
        for (int t = 0; t < 4; ++t)
            for (int b = ty0; b < 32; b += 16) {
                int n = nb + t * 32 + tx;
                tiles[t * 1056 + b * 33 + tx] =
                    (n < N) ? s[(size_t)b * N + n] : 0.f;
            }
        __syncthreads();
#pragma unroll
        for (int t = 0; t < 4; ++t)
            for (int nn0 = ty0; nn0 < 32; nn0 += 16) {
                int nn = nb + t * 32 + nn0;
                if (nn < N)
                    sTb[(size_t)nn * 32 + tx] = f2bf(tiles[t * 1056 + tx * 33 + nn0]);
            }
    }

    cooperative_groups::this_grid().sync();

    // ---------------- phase 2: accfin for range bid ----------------
    {
        int r = bid;
        int base = r * RB;
        float* acc    = (float*)smem;                    // 2112 f32
        int2*  sorted = (int2*)(smem + RB * 33);         // byte off 8448 (16-al)
        int*   hstart = smem + RB * 33 + 2 * CAPL;       // 6208
        int*   hcur   = hstart + RB;                     // 6272

        for (int i = tid; i < RB * 33; i += 512) acc[i] = 0.f;

        int b0 = r * CAP;
        int b1 = b0 + min(cursors[r], CAP);
        int q = tid & 7;                 // batches 4q..4q+3
        int p = (tid >> 3) & 7;          // record slot 0..7
        int wid = tid >> 6;              // wave -> nodes [wid*8, wid*8+8)
        int lane = tid & 63;

        for (int t = b0; t < b1; t += CAPL) {
            int m = min(CAPL, b1 - t);
            if (tid < RB) hstart[tid] = 0;
            __syncthreads();             // also orders acc zeroing (1st round)
            // register-stage 4 records/thread (single staging read)
            int2 rc[4];
            int rb = tid * 4;
            if (rb + 4 <= m) {
                const int4* sp = reinterpret_cast<const int4*>(&staging[t + rb]);
                int4 a = sp[0], b = sp[1];
                rc[0] = make_int2(a.x, a.y); rc[1] = make_int2(a.z, a.w);
                rc[2] = make_int2(b.x, b.y); rc[3] = make_int2(b.z, b.w);
            } else {
#pragma unroll
                for (int j = 0; j < 4; ++j)
                    if (rb + j < m) rc[j] = staging[t + rb + j];
            }
#pragma unroll
            for (int j = 0; j < 4; ++j)
                if (rb + j < m)
                    atomicAdd(&hstart[((unsigned)rc[j].x) >> 16], 1);
            __syncthreads();
            // wave-0 shuffle scan over 64 bins
            if (tid < 64) {
                int v = hstart[lane];
                int incl = v;
#pragma unroll
                for (int off = 1; off < 64; off <<= 1) {
                    int tv = __shfl_up(incl, off, 64);
                    if (lane >= off) incl += tv;
                }
                hstart[lane] = incl - v;
                hcur[lane]   = incl - v;
            }
            __syncthreads();
#pragma unroll
            for (int j = 0; j < 4; ++j)
                if (rb + j < m) {
                    int pos = atomicAdd(&hcur[((unsigned)rc[j].x) >> 16], 1);
                    sorted[pos] = rc[j];
                }
            __syncthreads();
            // gather: wave owns 8 nodes; 8 slots; owner-only acc adds
#pragma unroll
            for (int k = 0; k < 8; ++k) {
                int nl = wid * 8 + k;
                int beg = hstart[nl], end = hcur[nl];
                float a0 = 0.f, a1 = 0.f, a2 = 0.f, a3 = 0.f;
                for (int e = beg + p; e < end; e += 8) {
                    int2 rcv = sorted[e];
                    float w = __int_as_float(rcv.y);
                    uint2 u2 = *reinterpret_cast<const uint2*>(
                        sTb + (size_t)(rcv.x & 0xffff) * 32 + 4 * q);
                    a0 += w * __uint_as_float(u2.x << 16);
                    a1 += w * __uint_as_float(u2.x & 0xffff0000u);
                    a2 += w * __uint_as_float(u2.y << 16);
                    a3 += w * __uint_as_float(u2.y & 0xffff0000u);
                }
#pragma unroll
                for (int off = 8; off < 64; off <<= 1) {
                    a0 += __shfl_xor(a0, off, 64);
                    a1 += __shfl_xor(a1, off, 64);
                    a2 += __shfl_xor(a2, off, 64);
                    a3 += __shfl_xor(a3, off, 64);
                }
                if (lane < 8) {
                    float* ap = &acc[nl * 33 + 4 * q];
                    ap[0] += a0; ap[1] += a1; ap[2] += a2; ap[3] += a3;
                }
            }
            __syncthreads();
        }

        // epilogue: tanh / x-clamp, coalesced ns + y writes
        for (int v = tid; v < RB * BATCH; v += 512) {
            int nl = v & (RB - 1);
            int b  = v >> RB_LOG;
            int node = base + nl;
            if (node >= N) continue;
            float val;
            if (node < N_IN)
                val = x[b * N_IN + node];
            else
                val = tanhf(bias[node] + response[node] * acc[nl * 33 + b]);
            ns[(size_t)b * N + node] = val;
            int k = node - (N - N_OUT);
            if (k >= 0) y[b * N_OUT + k] = val;
        }
    }
}

// ================= fallback: r16 two-kernel path =================
__global__ __launch_bounds__(1024)
void fpart_kernel(const float* __restrict__ s, unsigned short* __restrict__ sTb,
                  int N, int PB,
                  const int* __restrict__ edge_src,
                  const int* __restrict__ edge_dst,
                  const float* __restrict__ weight,
                  int* __restrict__ cursors,
                  int2* __restrict__ staging,
                  int E, int R, int CAP) {
    __shared__ int shbuf[4224];
    int tid = threadIdx.x;
    if ((int)blockIdx.x >= PB) {
        float* tiles = (float*)shbuf;
        int tx = tid & 31;
        int ty = tid >> 5;
        int nb = ((int)blockIdx.x - PB) * 128;
#pragma unroll
        for (int t = 0; t < 4; ++t) {
            int n = nb + t * 32 + tx;
            tiles[t * 1056 + ty * 33 + tx] = (n < N) ? s[(size_t)ty * N + n] : 0.f;
        }
        __syncthreads();
#pragma unroll
        for (int t = 0; t < 4; ++t) {
            int nn = nb + t * 32 + ty;
            if (nn < N)
                sTb[(size_t)nn * 32 + tx] = f2bf(tiles[t * 1056 + tx * 33 + ty]);
        }
        return;
    }
    int* h    = shbuf;
    int* lcur = shbuf + MAXR;
    for (int i = tid; i < R; i += 1024) h[i] = 0;
    __syncthreads();
    int e0 = blockIdx.x * PCHF;
    int e1 = min(e0 + PCHF, E);
    int dd[8], ss[8]; float ww[8];
#pragma unroll
    for (int it = 0; it < 2; ++it) {
        int e = e0 + it * 4096 + tid * 4;
#pragma unroll
        for (int j = 0; j < 4; ++j) dd[it * 4 + j] = -1;
        if (e + 4 <= e1) {
            int4 d4 = *reinterpret_cast<const int4*>(edge_dst + e);
            int4 s4 = *reinterpret_cast<const int4*>(edge_src + e);
            float4 w4 = *reinterpret_cast<const float4*>(weight + e);
            dd[it*4+0]=d4.x; dd[it*4+1]=d4.y; dd[it*4+2]=d4.z; dd[it*4+3]=d4.w;
            ss[it*4+0]=s4.x; ss[it*4+1]=s4.y; ss[it*4+2]=s4.z; ss[it*4+3]=s4.w;
            ww[it*4+0]=w4.x; ww[it*4+1]=w4.y; ww[it*4+2]=w4.z; ww[it*4+3]=w4.w;
        } else {
#pragma unroll
            for (int j = 0; j < 4; ++j) {
                if (e + j < e1) {
                    dd[it*4+j] = edge_dst[e + j];
                    ss[it*4+j] = edge_src[e + j];
                    ww[it*4+j] = weight[e + j];
                }
            }
        }
#pragma unroll
        for (int j = 0; j < 4; ++j) {
            int idx = it * 4 + j;
            if (dd[idx] >= N_IN) atomicAdd(&h[dd[idx] >> RB_LOG], 1);
        }
    }
    __syncthreads();
    for (int i = tid; i < R; i += 1024) {
        int c = h[i];
        lcur[i] = c ? (i * CAP + atomicAdd(&cursors[i], c)) : 0;
    }
    __syncthreads();
#pragma unroll
    for (int idx = 0; idx < 8; ++idx) {
        if (dd[idx] >= N_IN) {
            int rng = dd[idx] >> RB_LOG;
            int pos = atomicAdd(&lcur[rng], 1);
            if (pos < (rng + 1) * CAP)
                staging[pos] = make_int2(((dd[idx] & (RB - 1)) << 16) | ss[idx],
                                         __float_as_int(ww[idx]));
        }
    }
}

__global__ __launch_bounds__(512)
void accfin_kernel(const unsigned short* __restrict__ sTb,
                   const int2* __restrict__ staging,
                   const int* __restrict__ cursors,
                   const float* __restrict__ x,
                   const float* __restrict__ bias,
                   const float* __restrict__ response,
                   float* __restrict__ ns, float* __restrict__ y,
                   int N, int CAP) {
    __shared__ float acc[RB * 33];
    __shared__ int2  sorted[CAPL];
    __shared__ int   hstart[RB];
    __shared__ int   hcur[RB];
    int tid = threadIdx.x;
    int r = blockIdx.x;
    int base = r * RB;
    for (int i = tid; i < RB * 33; i += 512) acc[i] = 0.f;
    int b0 = r * CAP;
    int b1 = b0 + min(cursors[r], CAP);
    int q = tid & 7;
    int p = (tid >> 3) & 7;
    int wid = tid >> 6;
    int lane = tid & 63;
    for (int t = b0; t < b1; t += CAPL) {
        int m = min(CAPL, b1 - t);
        if (tid < RB) hstart[tid] = 0;
        __syncthreads();
        for (int i = tid; i < m; i += 512)
            atomicAdd(&hstart[((unsigned)staging[t + i].x) >> 16], 1);
        __syncthreads();
        if (tid < 64) {
            int v = hstart[lane];
            int incl = v;
#pragma unroll
            for (int off = 1; off < 64; off <<= 1) {
                int tv = __shfl_up(incl, off, 64);
                if (lane >= off) incl += tv;
            }
            hstart[lane] = incl - v;
            hcur[lane]   = incl - v;
        }
        __syncthreads();
        for (int i = tid; i < m; i += 512) {
            int2 rc = staging[t + i];
            int pos = atomicAdd(&hcur[((unsigned)rc.x) >> 16], 1);
            sorted[pos] = rc;
        }
        __syncthreads();
#pragma unroll
        for (int k = 0; k < 8; ++k) {
            int nl = wid * 8 + k;
            int beg = hstart[nl], end = hcur[nl];
            float a0 = 0.f, a1 = 0.f, a2 = 0.f, a3 = 0.f;
            for (int e = beg + p; e < end; e += 8) {
                int2 rc = sorted[e];
                float w = __int_as_float(rc.y);
                uint2 u2 = *reinterpret_cast<const uint2*>(
                    sTb + (size_t)(rc.x & 0xffff) * 32 + 4 * q);
                a0 += w * __uint_as_float(u2.x << 16);
                a1 += w * __uint_as_float(u2.x & 0xffff0000u);
                a2 += w * __uint_as_float(u2.y << 16);
                a3 += w * __uint_as_float(u2.y & 0xffff0000u);
            }
#pragma unroll
            for (int off = 8; off < 64; off <<= 1) {
                a0 += __shfl_xor(a0, off, 64);
                a1 += __shfl_xor(a1, off, 64);
                a2 += __shfl_xor(a2, off, 64);
                a3 += __shfl_xor(a3, off, 64);
            }
            if (lane < 8) {
                float* ap = &acc[nl * 33 + 4 * q];
                ap[0] += a0; ap[1] += a1; ap[2] += a2; ap[3] += a3;
            }
        }
        __syncthreads();
    }
    for (int v = tid; v < RB * BATCH; v += 512) {
        int nl = v & (RB - 1);
        int b  = v >> RB_LOG;
        int node = base + nl;
        if (node >= N) continue;
        float val;
        if (node < N_IN)
            val = x[b * N_IN + node];
        else
            val = tanhf(bias[node] + response[node] * acc[nl * 33 + b]);
        ns[(size_t)b * N + node] = val;
        int k = node - (N - N_OUT);
        if (k >= 0) y[b * N_OUT + k] = val;
    }
}

// ---- last-resort fallback (round-1) kernels ----
__global__ void edge_kernel_fb(const float* __restrict__ states,
                               const float* __restrict__ weight,
                               const int* __restrict__ edge_src,
                               const int* __restrict__ edge_dst,
                               float* __restrict__ agg, int E, int N) {
    int e = blockIdx.x * blockDim.x + threadIdx.x;
    if (e >= E) return;
    int s = edge_src[e];
    int d = edge_dst[e];
    float w = weight[e];
#pragma unroll
    for (int b = 0; b < BATCH; ++b)
        atomicAdd(agg + (size_t)b * N + d, w * states[(size_t)b * N + s]);
}

__global__ void finish_kernel_fb(const float* __restrict__ x,
                                 const float* __restrict__ agg,
                                 const float* __restrict__ bias,
                                 const float* __restrict__ response,
                                 float* __restrict__ y, float* __restrict__ ns,
                                 int N) {
    int n = blockIdx.x * blockDim.x + threadIdx.x;
    int b = blockIdx.y;
    if (n >= N) return;
    float v;
    if (n < N_IN) v = x[b * N_IN + n];
    else          v = tanhf(bias[n] + response[n] * agg[(size_t)b * N + n]);
    ns[(size_t)b * N + n] = v;
    int n0 = N - N_OUT;
    if (n >= n0) y[b * N_OUT + (n - n0)] = v;
}

extern "C" void kernel_launch(void* const* d_in, const int* in_sizes, int n_in,
                              void* d_out, int out_size, void* d_ws, size_t ws_size,
                              hipStream_t stream) {
    const float* states   = (const float*)d_in[1];
    const float* weight   = (const float*)d_in[2];
    const float* bias     = (const float*)d_in[3];
    const float* response = (const float*)d_in[4];
    const int*   edge_src = (const int*)d_in[5];
    const int*   edge_dst = (const int*)d_in[6];
    const float* x        = (const float*)d_in[0];

    int N = in_sizes[3];          // 50000
    int E = in_sizes[5];          // 800000

    float* y  = (float*)d_out;                   // (B, N_OUT)
    float* ns = (float*)d_out + BATCH * N_OUT;   // (B, N)

    int R   = (N + RB - 1) / RB;                 // 782
    int TG  = (N + 127) / 128;                   // 391
    int PBc = (E + PCHC - 1) / PCHC;             // 196 (coop)
    int PBf = (E + PCHF - 1) / PCHF;             // 98  (fallback)

    int mean = (E + R - 1) / R;
    int CAP  = ((4 * mean + CAPL - 1) / CAPL) * CAPL;   // 4096

    size_t staging_bytes = ((size_t)R * CAP * 8 + 15) & ~(size_t)15;
    size_t sTb_bytes     = ((size_t)N * 32 * 2 + 15) & ~(size_t)15;
    size_t cur_bytes     = ((size_t)R * 4 + 15) & ~(size_t)15;
    size_t needed = staging_bytes + sTb_bytes + cur_bytes + 64;

    if (ws_size < needed || R > MAXR || N > 65536) {
        // last resort: atomic-scatter path (needs 6.4 MB)
        float* agg = (float*)d_ws;
        hipMemsetAsync(agg, 0, (size_t)BATCH * N * sizeof(float), stream);
        int egrid = (E + 255) / 256;
        edge_kernel_fb<<<egrid, 256, 0, stream>>>(states, weight, edge_src,
                                                  edge_dst, agg, E, N);
        dim3 fgrid((N + 255) / 256, BATCH);
        finish_kernel_fb<<<fgrid, 256, 0, stream>>>(x, agg, bias, response,
                                                    y, ns, N);
        return;
    }

    char* p = (char*)d_ws;
    int2*           staging = (int2*)p;           p += staging_bytes;
    unsigned short* sTb     = (unsigned short*)p; p += sTb_bytes;
    int*            cursors = (int*)p;

    hipMemsetAsync(cursors, 0, (size_t)R * 4, stream);

    // cooperative-capacity check (host-side queries only)
    bool coop = (PBc + TG <= R) && (2 * R <= SMEM_INTS);
    int dev = 0, cus = 0, blocksPerCu = 0;
    if (coop && hipGetDevice(&dev) == hipSuccess &&
        hipDeviceGetAttribute(&cus, hipDeviceAttributeMultiprocessorCount,
                              dev) == hipSuccess &&
        hipOccupancyMaxActiveBlocksPerMultiprocessor(
            &blocksPerCu, fused_kernel, 512, 0) == hipSuccess) {
        coop = (blocksPerCu * cus >= R);
    } else {
        coop = false;
    }

    if (coop) {
        void* args[] = {
            (void*)&states, (void*)&sTb, (void*)&edge_src, (void*)&edge_dst,
            (void*)&weight, (void*)&cursors, (void*)&staging, (void*)&x,
            (void*)&bias, (void*)&response, (void*)&ns, (void*)&y,
            (void*)&N, (void*)&E, (void*)&R, (void*)&CAP,
            (void*)&PBc, (void*)&TG};
        hipError_t err = hipLaunchCooperativeKernel(
            (const void*)fused_kernel, dim3(R), dim3(512), args, 0, stream);
        if (err == hipSuccess) return;
        // fall through to 2-kernel path on launch failure
    }

    // fallback: r16 two-kernel path
    fpart_kernel<<<PBf + TG, 1024, 0, stream>>>(
        states, sTb, N, PBf, edge_src, edge_dst, weight,
        cursors, staging, E, R, CAP);
    accfin_kernel<<<R, 512, 0, stream>>>(sTb, staging, cursors, x,
                                         bias, response, ns, y, N, CAP);
}

// Round 18
// 46.214 us; speedup vs baseline: 1.0062x; 1.0062x over previous
//
#include <hip/hip_runtime.h>

// WiredRNN one step. Slab partition + fused sort-gather-activate.
// NO f32 atomics (measured wall: 25.6M LDS f32 atomicAdd = 170-180us).
// r18: (a) fpart 512thr blocks (196 partition @PCH4096 + 391 transpose,
//      4 blocks/CU, tail-free); (b) accfin reads staging ONCE into
//      registers (hist+place from regs) -- deletes 6.4MB second pass.
//      Coop fusion abandoned: not graph-capturable (r17: timed graph fell
//      back; fused ran only uncaptured at 148us with VGPR=28 spills).
// 3 dispatches: memset(cursors) ; fpart ; accfin.
// inputs: 0:x(B,512) 1:states(B,N) 2:weight(E) 3:bias(N) 4:response(N)
//         5:edge_src(E int32) 6:edge_dst(E int32)
// out: y(B,256) then new_states(B,N), f32, concatenated flat.

#define BATCH 32
#define N_IN 512
#define N_OUT 256
#define RB_LOG 6
#define RB 64            // nodes per range
#define CAPL 2048        // records per accfin round (16KB LDS)
#define MAXR 2048        // max ranges
#define PCH 4096         // edges per partition block (8/thread @512)

static __device__ __forceinline__ unsigned short f2bf(float f) {
    unsigned u = __float_as_uint(f);
    unsigned r = (u + 0x7fffu + ((u >> 16) & 1u)) >> 16;   // RNE
    return (unsigned short)r;
}

// ---- K0 (512 thr): {slab partition} || {transpose (B,N)->(N,32) bf16, x4} ----
__global__ __launch_bounds__(512)
void fpart_kernel(const float* __restrict__ s, unsigned short* __restrict__ sTb,
                  int N, int PB,
                  const int* __restrict__ edge_src,
                  const int* __restrict__ edge_dst,
                  const float* __restrict__ weight,
                  int* __restrict__ cursors,
                  int2* __restrict__ staging,
                  int E, int R, int CAP) {
    __shared__ int shbuf[4224];          // tiles 16.9KB  /  h+lcur 2*R ints
    int tid = threadIdx.x;
    if ((int)blockIdx.x >= PB) {
        // ------------- transpose: 4 tiles of 32 nodes, 512 thr -------------
        float* tiles = (float*)shbuf;    // [4][1056]
        int tx = tid & 31;
        int ty0 = tid >> 5;              // 0..15
        int nb = ((int)blockIdx.x - PB) * 128;
#pragma unroll
        for (int t = 0; t < 4; ++t)
            for (int b = ty0; b < 32; b += 16) {
                int n = nb + t * 32 + tx;
                tiles[t * 1056 + b * 33 + tx] =
                    (n < N) ? s[(size_t)b * N + n] : 0.f;      // b = batch
            }
        __syncthreads();
#pragma unroll
        for (int t = 0; t < 4; ++t)
            for (int nn0 = ty0; nn0 < 32; nn0 += 16) {
                int nn = nb + t * 32 + nn0;
                if (nn < N)
                    sTb[(size_t)nn * 32 + tx] =
                        f2bf(tiles[t * 1056 + tx * 33 + nn0]);
            }
        return;
    }
    // ---------------- partition: 4096 edges, 8/thread in regs ----------------
    int* h    = shbuf;
    int* lcur = shbuf + MAXR;
    for (int i = tid; i < R; i += 512) h[i] = 0;
    __syncthreads();
    int e0 = blockIdx.x * PCH;
    int e1 = min(e0 + PCH, E);
    int dd[8], ss[8]; float ww[8];
#pragma unroll
    for (int it = 0; it < 2; ++it) {
        int e = e0 + it * 2048 + tid * 4;
#pragma unroll
        for (int j = 0; j < 4; ++j) dd[it * 4 + j] = -1;
        if (e + 4 <= e1) {
            int4 d4 = *reinterpret_cast<const int4*>(edge_dst + e);
            int4 s4 = *reinterpret_cast<const int4*>(edge_src + e);
            float4 w4 = *reinterpret_cast<const float4*>(weight + e);
            dd[it*4+0]=d4.x; dd[it*4+1]=d4.y; dd[it*4+2]=d4.z; dd[it*4+3]=d4.w;
            ss[it*4+0]=s4.x; ss[it*4+1]=s4.y; ss[it*4+2]=s4.z; ss[it*4+3]=s4.w;
            ww[it*4+0]=w4.x; ww[it*4+1]=w4.y; ww[it*4+2]=w4.z; ww[it*4+3]=w4.w;
        } else {
#pragma unroll
            for (int j = 0; j < 4; ++j) {
                if (e + j < e1) {
                    dd[it*4+j] = edge_dst[e + j];
                    ss[it*4+j] = edge_src[e + j];
                    ww[it*4+j] = weight[e + j];
                }
            }
        }
#pragma unroll
        for (int j = 0; j < 4; ++j) {
            int idx = it * 4 + j;
            if (dd[idx] >= N_IN) atomicAdd(&h[dd[idx] >> RB_LOG], 1);
        }
    }
    __syncthreads();
    // reserve slab slices: one global atomic per non-empty (block, range)
    for (int i = tid; i < R; i += 512) {
        int c = h[i];
        lcur[i] = c ? (i * CAP + atomicAdd(&cursors[i], c)) : 0;
    }
    __syncthreads();
#pragma unroll
    for (int idx = 0; idx < 8; ++idx) {
        if (dd[idx] >= N_IN) {
            int rng = dd[idx] >> RB_LOG;
            int pos = atomicAdd(&lcur[rng], 1);
            if (pos < (rng + 1) * CAP)   // overflow clamp (never at 4x mean)
                staging[pos] = make_int2(((dd[idx] & (RB - 1)) << 16) | ss[idx],
                                         __float_as_int(ww[idx]));
        }
    }
}

// ---- K1 (512 thr): per-range sort + 8-slot register gather + activation ----
// Records register-staged ONCE (4/thread); hist + place from registers.
__global__ __launch_bounds__(512)
void accfin_kernel(const unsigned short* __restrict__ sTb,
                   const int2* __restrict__ staging,
                   const int* __restrict__ cursors,
                   const float* __restrict__ x,
                   const float* __restrict__ bias,
                   const float* __restrict__ response,
                   float* __restrict__ ns, float* __restrict__ y,
                   int N, int CAP) {
    __shared__ float acc[RB * 33];       // 8.4 KB, owner-wave writes only
    __shared__ int2  sorted[CAPL];       // 16 KB
    __shared__ int   hstart[RB];
    __shared__ int   hcur[RB];
    int tid = threadIdx.x;
    int r = blockIdx.x;
    int base = r * RB;
    for (int i = tid; i < RB * 33; i += 512) acc[i] = 0.f;

    int b0 = r * CAP;
    int b1 = b0 + min(cursors[r], CAP);
    int q = tid & 7;                     // batches 4q..4q+3
    int p = (tid >> 3) & 7;              // record slot 0..7
    int wid = tid >> 6;                  // wave -> nodes [wid*8, wid*8+8)
    int lane = tid & 63;

    for (int t = b0; t < b1; t += CAPL) {
        int m = min(CAPL, b1 - t);
        if (tid < RB) hstart[tid] = 0;
        __syncthreads();                 // also orders acc zeroing (round 1)
        // register-stage 4 records/thread (single staging read)
        int2 rc[4];
        int rb = tid * 4;
        if (rb + 4 <= m) {
            const int4* sp = reinterpret_cast<const int4*>(&staging[t + rb]);
            int4 a = sp[0], b = sp[1];
            rc[0] = make_int2(a.x, a.y); rc[1] = make_int2(a.z, a.w);
            rc[2] = make_int2(b.x, b.y); rc[3] = make_int2(b.z, b.w);
        } else {
#pragma unroll
            for (int j = 0; j < 4; ++j)
                if (rb + j < m) rc[j] = staging[t + rb + j];
        }
#pragma unroll
        for (int j = 0; j < 4; ++j)
            if (rb + j < m)
                atomicAdd(&hstart[((unsigned)rc[j].x) >> 16], 1);
        __syncthreads();
        // wave-0 shuffle scan over RB=64 bins (no block barriers)
        if (tid < 64) {
            int v = hstart[lane];
            int incl = v;
#pragma unroll
            for (int off = 1; off < 64; off <<= 1) {
                int tv = __shfl_up(incl, off, 64);
                if (lane >= off) incl += tv;
            }
            hstart[lane] = incl - v;     // exclusive
            hcur[lane]   = incl - v;
        }
        __syncthreads();
#pragma unroll
        for (int j = 0; j < 4; ++j)
            if (rb + j < m) {
                int pos = atomicAdd(&hcur[((unsigned)rc[j].x) >> 16], 1);
                sorted[pos] = rc[j];
            }
        __syncthreads();
        // gather: wave owns 8 nodes; 8 slots in flight; owner-only acc adds
#pragma unroll
        for (int k = 0; k < 8; ++k) {
            int nl = wid * 8 + k;
            int beg = hstart[nl], end = hcur[nl];
            float a0 = 0.f, a1 = 0.f, a2 = 0.f, a3 = 0.f;
            for (int e = beg + p; e < end; e += 8) {
                int2 rcv = sorted[e];                      // broadcast read
                float w = __int_as_float(rcv.y);
                uint2 u2 = *reinterpret_cast<const uint2*>(
                    sTb + (size_t)(rcv.x & 0xffff) * 32 + 4 * q);
                a0 += w * __uint_as_float(u2.x << 16);
                a1 += w * __uint_as_float(u2.x & 0xffff0000u);
                a2 += w * __uint_as_float(u2.y << 16);
                a3 += w * __uint_as_float(u2.y & 0xffff0000u);
            }
#pragma unroll
            for (int off = 8; off < 64; off <<= 1) {
                a0 += __shfl_xor(a0, off, 64);
                a1 += __shfl_xor(a1, off, 64);
                a2 += __shfl_xor(a2, off, 64);
                a3 += __shfl_xor(a3, off, 64);
            }
            if (lane < 8) {                                 // p == 0 lanes
                float* ap = &acc[nl * 33 + 4 * q];
                ap[0] += a0; ap[1] += a1; ap[2] += a2; ap[3] += a3;
            }
        }
        __syncthreads();
    }

    // epilogue: tanh / x-clamp, coalesced ns + y writes
    for (int v = tid; v < RB * BATCH; v += 512) {
        int nl = v & (RB - 1);
        int b  = v >> RB_LOG;
        int node = base + nl;
        if (node >= N) continue;
        float val;
        if (node < N_IN)
            val = x[b * N_IN + node];
        else
            val = tanhf(bias[node] + response[node] * acc[nl * 33 + b]);
        ns[(size_t)b * N + node] = val;
        int k = node - (N - N_OUT);
        if (k >= 0) y[b * N_OUT + k] = val;
    }
}

// ---- last-resort fallback (round-1) kernels ----
__global__ void edge_kernel_fb(const float* __restrict__ states,
                               const float* __restrict__ weight,
                               const int* __restrict__ edge_src,
                               const int* __restrict__ edge_dst,
                               float* __restrict__ agg, int E, int N) {
    int e = blockIdx.x * blockDim.x + threadIdx.x;
    if (e >= E) return;
    int s = edge_src[e];
    int d = edge_dst[e];
    float w = weight[e];
#pragma unroll
    for (int b = 0; b < BATCH; ++b)
        atomicAdd(agg + (size_t)b * N + d, w * states[(size_t)b * N + s]);
}

__global__ void finish_kernel_fb(const float* __restrict__ x,
                                 const float* __restrict__ agg,
                                 const float* __restrict__ bias,
                                 const float* __restrict__ response,
                                 float* __restrict__ y, float* __restrict__ ns,
                                 int N) {
    int n = blockIdx.x * blockDim.x + threadIdx.x;
    int b = blockIdx.y;
    if (n >= N) return;
    float v;
    if (n < N_IN) v = x[b * N_IN + n];
    else          v = tanhf(bias[n] + response[n] * agg[(size_t)b * N + n]);
    ns[(size_t)b * N + n] = v;
    int n0 = N - N_OUT;
    if (n >= n0) y[b * N_OUT + (n - n0)] = v;
}

extern "C" void kernel_launch(void* const* d_in, const int* in_sizes, int n_in,
                              void* d_out, int out_size, void* d_ws, size_t ws_size,
                              hipStream_t stream) {
    const float* x        = (const float*)d_in[0];
    const float* states   = (const float*)d_in[1];
    const float* weight   = (const float*)d_in[2];
    const float* bias     = (const float*)d_in[3];
    const float* response = (const float*)d_in[4];
    const int*   edge_src = (const int*)d_in[5];
    const int*   edge_dst = (const int*)d_in[6];

    int N = in_sizes[3];          // 50000
    int E = in_sizes[5];          // 800000

    float* y  = (float*)d_out;                   // (B, N_OUT)
    float* ns = (float*)d_out + BATCH * N_OUT;   // (B, N)

    int TG = (N + 127) / 128;                    // 391
    int R  = (N + RB - 1) / RB;                  // 782
    int PB = (E + PCH - 1) / PCH;                // 196

    // slab capacity: 4x mean load, rounded up to CAPL multiple
    int mean = (E + R - 1) / R;                  // ~1023
    int CAP  = ((4 * mean + CAPL - 1) / CAPL) * CAPL;   // 4096

    size_t staging_bytes = ((size_t)R * CAP * 8 + 15) & ~(size_t)15;  // ~25.6MB
    size_t sTb_bytes     = ((size_t)N * 32 * 2 + 15) & ~(size_t)15;
    size_t cur_bytes     = ((size_t)R * 4 + 15) & ~(size_t)15;
    size_t needed = staging_bytes + sTb_bytes + cur_bytes + 64;

    if (ws_size < needed || R > MAXR || N > 65536) {
        // fallback: atomic-scatter path (needs 6.4 MB)
        float* agg = (float*)d_ws;
        hipMemsetAsync(agg, 0, (size_t)BATCH * N * sizeof(float), stream);
        int egrid = (E + 255) / 256;
        edge_kernel_fb<<<egrid, 256, 0, stream>>>(states, weight, edge_src,
                                                  edge_dst, agg, E, N);
        dim3 fgrid((N + 255) / 256, BATCH);
        finish_kernel_fb<<<fgrid, 256, 0, stream>>>(x, agg, bias, response,
                                                    y, ns, N);
        return;
    }

    char* p = (char*)d_ws;
    int2*           staging = (int2*)p;           p += staging_bytes;
    unsigned short* sTb     = (unsigned short*)p; p += sTb_bytes;
    int*            cursors = (int*)p;

    hipMemsetAsync(cursors, 0, (size_t)R * 4, stream);

    // K0: slab partition (blocks [0,PB)) || transpose x4 (blocks [PB, PB+TG))
    fpart_kernel<<<PB + TG, 512, 0, stream>>>(
        states, sTb, N, PB, edge_src, edge_dst, weight,
        cursors, staging, E, R, CAP);

    // K1: fused sort + 8-slot register gather + tanh + output
    accfin_kernel<<<R, 512, 0, stream>>>(sTb, staging, cursors, x,
                                         bias, response, ns, y, N, CAP);
}